// Round 1
// baseline (10620.782 us; speedup 1.0000x reference)
//
#include <hip/hip_runtime.h>
#include <math.h>

// ---------------------------------------------------------------------------
// Shapes (fixed by the reference): N=50000 nodes, E=800000 edges, feature 64,
// message hidden 128, 3 MPN steps, 17 types.
// Strategy: one thread per row/edge. Weights are wave-uniform -> scalar loads
// (s_load) on the SMEM pipe; x/h stay in VGPRs; hidden-broadcast in layer 2
// goes through a per-thread LDS strip (layout [k][lane], conflict-free).
// ---------------------------------------------------------------------------

__device__ __forceinline__ unsigned fkey(float f) {
    unsigned u = __float_as_uint(f);
    return (u & 0x80000000u) ? ~u : (u | 0x80000000u);
}
__device__ __forceinline__ float funkey(unsigned k) {
    return (k & 0x80000000u) ? __uint_as_float(k & 0x7FFFFFFFu) : __uint_as_float(~k);
}

// h[c] += sum_k x[k] * w[k*wld + c]  for a 64-long k-chunk, c in [0,64)
__device__ __forceinline__ void accum_part64(const float* __restrict__ xp,
                                             const float* __restrict__ w, const int wld,
                                             float* __restrict__ h)
{
#pragma unroll 1
    for (int kc = 0; kc < 64; kc += 8) {
        float4 a = *(const float4*)(xp + kc);
        float4 b = *(const float4*)(xp + kc + 4);
        float xs[8] = {a.x, a.y, a.z, a.w, b.x, b.y, b.z, b.w};
        const float* __restrict__ wr = w + (size_t)kc * wld;
#pragma unroll
        for (int kk = 0; kk < 8; kk++) {
#pragma unroll
            for (int c = 0; c < 64; c++)
                h[c] = fmaf(xs[kk], wr[(size_t)kk * wld + c], h[c]);
        }
    }
}

// acc[c] += sum_k relu(h[k]) * w[k*64+c] ; h broadcast via per-thread LDS strip
__device__ __forceinline__ void layer2_strip_relu(float* __restrict__ strip, int lane,
                                                  const float* __restrict__ h,
                                                  const float* __restrict__ w,
                                                  float* __restrict__ acc)
{
#pragma unroll
    for (int k = 0; k < 64; k++) strip[k * 64 + lane] = fmaxf(h[k], 0.f);
    // same-thread LDS round-trip, wave-coherent: no barrier needed
#pragma unroll 1
    for (int k = 0; k < 64; k++) {
        float hv = strip[k * 64 + lane];
        const float* __restrict__ wr = w + (size_t)k * 64;
#pragma unroll
        for (int c = 0; c < 64; c++) acc[c] = fmaf(hv, wr[c], acc[c]);
    }
}

__device__ __forceinline__ void store_row64(float* __restrict__ dst, const float* __restrict__ acc)
{
#pragma unroll
    for (int i = 0; i < 16; i++)
        ((float4*)dst)[i] = make_float4(acc[4 * i], acc[4 * i + 1], acc[4 * i + 2], acc[4 * i + 3]);
}

// ---------------- encoder: out = relu(in@W1+b1)@W2+b2, rows of 64 ----------
__global__ __launch_bounds__(64)
void mlp64_kernel(const float* __restrict__ in,
                  const float* __restrict__ w1, const float* __restrict__ b1,
                  const float* __restrict__ w2, const float* __restrict__ b2,
                  float* __restrict__ out, int M)
{
    __shared__ float strip[64 * 64];
    int r = blockIdx.x * 64 + threadIdx.x;
    if (r >= M) return;
    int lane = threadIdx.x;
    const float* xp = in + (size_t)r * 64;
    float h[64];
#pragma unroll
    for (int c = 0; c < 64; c++) h[c] = b1[c];
    accum_part64(xp, w1, 64, h);
    float acc[64];
#pragma unroll
    for (int c = 0; c < 64; c++) acc[c] = b2[c];
    layer2_strip_relu(strip, lane, h, w2, acc);
    store_row64(out + (size_t)r * 64, acc);
}

// ---------------- message MLP + scatter-add aggregation --------------------
__global__ __launch_bounds__(64)
void msg_kernel(const float* __restrict__ nf, const float* __restrict__ ef,
                const int* __restrict__ src, const int* __restrict__ tgt,
                const float* __restrict__ w1, const float* __restrict__ b1,
                const float* __restrict__ w2, const float* __restrict__ b2,
                float* __restrict__ m_out, float* __restrict__ aggr, int E)
{
    __shared__ float strip[64 * 64];
    int e = blockIdx.x * 64 + threadIdx.x;
    if (e >= E) return;
    int lane = threadIdx.x;
    int s = src[e], t = tgt[e];
    const float* __restrict__ pa = nf + (size_t)s * 64;
    const float* __restrict__ pb = nf + (size_t)t * 64;
    const float* __restrict__ pc = ef + (size_t)e * 64;

    float macc[64];
#pragma unroll
    for (int c = 0; c < 64; c++) macc[c] = b2[c];

#pragma unroll 1
    for (int half = 0; half < 2; half++) {
        float h[64];
#pragma unroll
        for (int c = 0; c < 64; c++) h[c] = b1[half * 64 + c];
        // me_w1 is [192][128]; concat order nf[src], nf[tgt], ef
        accum_part64(pa, w1 + half * 64, 128, h);
        accum_part64(pb, w1 + (size_t)64 * 128 + half * 64, 128, h);
        accum_part64(pc, w1 + (size_t)128 * 128 + half * 64, 128, h);
        // me_w2 is [128][64]
        layer2_strip_relu(strip, lane, h, w2 + (size_t)half * 64 * 64, macc);
    }
    store_row64(m_out + (size_t)e * 64, macc);
    float* __restrict__ ag = aggr + (size_t)t * 64;
#pragma unroll
    for (int c = 0; c < 64; c++) atomicAdd(ag + c, macc[c]);
}

// ---------------- node update: nf' = concat(nf, aggr) @ nu_w1 + b ----------
__global__ __launch_bounds__(64)
void node_update_kernel(const float* __restrict__ nf, const float* __restrict__ ag,
                        const float* __restrict__ w, const float* __restrict__ b,
                        float* __restrict__ out, int M)
{
    int r = blockIdx.x * 64 + threadIdx.x;
    if (r >= M) return;
    float acc[64];
#pragma unroll
    for (int c = 0; c < 64; c++) acc[c] = b[c];
    accum_part64(nf + (size_t)r * 64, w, 64, acc);
    accum_part64(ag + (size_t)r * 64, w + (size_t)64 * 64, 64, acc);
    store_row64(out + (size_t)r * 64, acc);
}

// ---------------- node heads: node_pred, class_pred+argmax, embedding ------
__global__ __launch_bounds__(256)
void heads_kernel(const float* __restrict__ nf,
                  const float* __restrict__ nc_w1, const float* __restrict__ nc_b1,
                  const float* __restrict__ nc_w2, const float* __restrict__ nc_b2,
                  const float* __restrict__ cl_w1, const float* __restrict__ cl_b1,
                  const float* __restrict__ cl_w2, const float* __restrict__ cl_b2,
                  const float* __restrict__ ce_w,  const float* __restrict__ ce_b,
                  float* __restrict__ node_pred, float* __restrict__ class_pred,
                  int* __restrict__ ntype, float* __restrict__ emb, int M)
{
    int r = blockIdx.x * blockDim.x + threadIdx.x;
    if (r >= M) return;
    const float* xp = nf + (size_t)r * 64;
    {
        float h[64];
#pragma unroll
        for (int c = 0; c < 64; c++) h[c] = nc_b1[c];
        accum_part64(xp, nc_w1, 64, h);
        float np = nc_b2[0];
#pragma unroll
        for (int k = 0; k < 64; k++) np = fmaf(fmaxf(h[k], 0.f), nc_w2[k], np);
        node_pred[r] = np;
    }
    {
        float h[64];
#pragma unroll
        for (int c = 0; c < 64; c++) h[c] = cl_b1[c];
        accum_part64(xp, cl_w1, 64, h);
        float cp[17];
#pragma unroll
        for (int j = 0; j < 17; j++) cp[j] = cl_b2[j];
#pragma unroll
        for (int k = 0; k < 64; k++) {
            float hv = fmaxf(h[k], 0.f);
#pragma unroll
            for (int j = 0; j < 17; j++) cp[j] = fmaf(hv, cl_w2[k * 17 + j], cp[j]);
        }
#pragma unroll
        for (int j = 0; j < 17; j++) class_pred[(size_t)r * 17 + j] = cp[j];
        float best = cp[0]; int bi = 0;          // jnp.argmax: first max index
#pragma unroll
        for (int j = 1; j < 17; j++) { if (cp[j] > best) { best = cp[j]; bi = j; } }
        ntype[r] = bi;
    }
    {
        float acc[64];
#pragma unroll
        for (int c = 0; c < 64; c++) acc[c] = ce_b[c];
        accum_part64(xp, ce_w, 64, acc);
        store_row64(emb + (size_t)r * 64, acc);
    }
}

// ---------------- segment-softmax passes -----------------------------------
__global__ void init_seg_kernel(unsigned* __restrict__ segmaxu, float* __restrict__ segsum, int n)
{
    int i = blockIdx.x * blockDim.x + threadIdx.x;
    if (i < n) { segmaxu[i] = 0x007FFFFFu /* fkey(-inf) */; segsum[i] = 0.f; }
}

__global__ __launch_bounds__(64)
void edge1_kernel(const float* __restrict__ ef,
                  const float* __restrict__ ec_w1, const float* __restrict__ ec_b1,
                  const float* __restrict__ ec_w2, const float* __restrict__ ec_b2,
                  const float* __restrict__ emb, const int* __restrict__ src,
                  const int* __restrict__ tgt, const int* __restrict__ ntype,
                  float* __restrict__ score, float* __restrict__ sigb,
                  int* __restrict__ seg, unsigned* __restrict__ segmaxu, int E)
{
    int e = blockIdx.x * 64 + threadIdx.x;
    if (e >= E) return;
    float h[64];
#pragma unroll
    for (int c = 0; c < 64; c++) h[c] = ec_b1[c];
    accum_part64(ef + (size_t)e * 64, ec_w1, 64, h);
    float ep = ec_b2[0];
#pragma unroll
    for (int k = 0; k < 64; k++) ep = fmaf(fmaxf(h[k], 0.f), ec_w2[k], ep);
    sigb[e] = 1.f / (1.f + expf(-ep));

    int s = src[e], t = tgt[e];
    const float* ea = emb + (size_t)s * 64;
    const float* eb = emb + (size_t)t * 64;
    float sc = 0.f;
#pragma unroll 1
    for (int kc = 0; kc < 64; kc += 4) {
        float4 ua = *(const float4*)(ea + kc);
        float4 ub = *(const float4*)(eb + kc);
        sc = fmaf(ua.x, ub.x, sc); sc = fmaf(ua.y, ub.y, sc);
        sc = fmaf(ua.z, ub.z, sc); sc = fmaf(ua.w, ub.w, sc);
    }
    score[e] = sc;
    int sg = t * 17 + ntype[s];
    seg[e] = sg;
    atomicMax(segmaxu + sg, fkey(sc));
}

__global__ void edge2_kernel(const float* __restrict__ score, const int* __restrict__ seg,
                             const unsigned* __restrict__ segmaxu, float* __restrict__ segsum,
                             float* __restrict__ exb, int E)
{
    int e = blockIdx.x * blockDim.x + threadIdx.x;
    if (e >= E) return;
    int sg = seg[e];
    float ex = expf(score[e] - funkey(segmaxu[sg]));
    exb[e] = ex;
    atomicAdd(segsum + sg, ex);
}

__global__ void edge3_kernel(const float* __restrict__ exb, const int* __restrict__ seg,
                             const float* __restrict__ segsum, const float* __restrict__ sigb,
                             float* __restrict__ out_edge, int E)
{
    int e = blockIdx.x * blockDim.x + threadIdx.x;
    if (e >= E) return;
    out_edge[e] = exb[e] / segsum[seg[e]] * sigb[e];
}

// ---------------------------------------------------------------------------
extern "C" void kernel_launch(void* const* d_in, const int* in_sizes, int n_in,
                              void* d_out, int out_size, void* d_ws, size_t ws_size,
                              hipStream_t stream)
{
    const float* x          = (const float*)d_in[0];
    const float* edge_attr  = (const float*)d_in[1];
    const int*   edge_index = (const int*)d_in[2];
    // d_in[3] node_types: unused by the reference
    const float* ne_w1 = (const float*)d_in[4],  *ne_b1 = (const float*)d_in[5];
    const float* ne_w2 = (const float*)d_in[6],  *ne_b2 = (const float*)d_in[7];
    const float* ee_w1 = (const float*)d_in[8],  *ee_b1 = (const float*)d_in[9];
    const float* ee_w2 = (const float*)d_in[10], *ee_b2 = (const float*)d_in[11];
    const float* me_w1 = (const float*)d_in[12], *me_b1 = (const float*)d_in[13];
    const float* me_w2 = (const float*)d_in[14], *me_b2 = (const float*)d_in[15];
    const float* nu_w1 = (const float*)d_in[16], *nu_b1 = (const float*)d_in[17];
    const float* ec_w1 = (const float*)d_in[18], *ec_b1 = (const float*)d_in[19];
    const float* ec_w2 = (const float*)d_in[20], *ec_b2 = (const float*)d_in[21];
    const float* nc_w1 = (const float*)d_in[22], *nc_b1 = (const float*)d_in[23];
    const float* nc_w2 = (const float*)d_in[24], *nc_b2 = (const float*)d_in[25];
    const float* cl_w1 = (const float*)d_in[26], *cl_b1 = (const float*)d_in[27];
    const float* cl_w2 = (const float*)d_in[28], *cl_b2 = (const float*)d_in[29];
    const float* ce_w  = (const float*)d_in[30], *ce_b  = (const float*)d_in[31];

    const int N = in_sizes[3];
    const int E = in_sizes[2] / 2;
    const int* src = edge_index;
    const int* tgt = edge_index + E;

    float* out      = (float*)d_out;
    float* out_edge = out;                              // [E]
    float* out_np   = out + E;                          // [N]
    float* out_cp   = out_np + N;                       // [N,17]
    float* out_nf   = out_cp + (size_t)17 * N;          // [N,64]
    float* out_ef   = out_nf + (size_t)64 * N;          // [E,64]

    float* p = (float*)d_ws;
    float* nfA    = p; p += (size_t)N * 64;
    float* nfB    = p; p += (size_t)N * 64;
    float* aggr   = p; p += (size_t)N * 64;
    float* emb    = p; p += (size_t)N * 64;
    float* efA    = p; p += (size_t)E * 64;
    float* score  = p; p += E;
    float* sigb   = p; p += E;
    float* exb    = p; p += E;
    float* segsum = p; p += (size_t)N * 17;
    unsigned* segmaxu = (unsigned*)p; p += (size_t)N * 17;
    int* seg   = (int*)p; p += E;
    int* ntype = (int*)p; p += N;

    const int gN = (N + 63) / 64, gE = (E + 63) / 64;

    // encoders
    mlp64_kernel<<<gN, 64, 0, stream>>>(x, ne_w1, ne_b1, ne_w2, ne_b2, nfA, N);
    mlp64_kernel<<<gE, 64, 0, stream>>>(edge_attr, ee_w1, ee_b1, ee_w2, ee_b2, efA, E);

    // 3 MPN steps; ef ping-pongs between efA and the final d_out ef slot so
    // step 3's messages land directly in d_out (and step 3's nf in d_out too)
    const float* nf_cur = nfA;
    const float* ef_cur = efA;
    for (int st = 0; st < 3; st++) {
        float* m_dst  = (st == 1) ? efA : out_ef;
        float* nf_dst = (st == 0) ? nfB : (st == 1) ? nfA : out_nf;
        hipMemsetAsync(aggr, 0, (size_t)N * 64 * sizeof(float), stream);
        msg_kernel<<<gE, 64, 0, stream>>>(nf_cur, ef_cur, src, tgt,
                                          me_w1, me_b1, me_w2, me_b2, m_dst, aggr, E);
        node_update_kernel<<<gN, 64, 0, stream>>>(nf_cur, aggr, nu_w1, nu_b1, nf_dst, N);
        nf_cur = nf_dst; ef_cur = m_dst;
    }

    // heads + type-constrained scatter-softmax
    heads_kernel<<<(N + 255) / 256, 256, 0, stream>>>(out_nf,
        nc_w1, nc_b1, nc_w2, nc_b2, cl_w1, cl_b1, cl_w2, cl_b2, ce_w, ce_b,
        out_np, out_cp, ntype, emb, N);
    init_seg_kernel<<<(N * 17 + 255) / 256, 256, 0, stream>>>(segmaxu, segsum, N * 17);
    edge1_kernel<<<gE, 64, 0, stream>>>(out_ef, ec_w1, ec_b1, ec_w2, ec_b2,
                                        emb, src, tgt, ntype, score, sigb, seg, segmaxu, E);
    edge2_kernel<<<(E + 255) / 256, 256, 0, stream>>>(score, seg, segmaxu, segsum, exb, E);
    edge3_kernel<<<(E + 255) / 256, 256, 0, stream>>>(exb, seg, segsum, sigb, out_edge, E);
}

// Round 2
// 4589.763 us; speedup vs baseline: 2.3140x; 2.3140x over previous
//
#include <hip/hip_runtime.h>
#include <math.h>

// ---------------------------------------------------------------------------
// N=50000 nodes, E=800000 edges, feat 64, msg hidden 128, 3 steps, 17 types.
// Round 2: MLPs as LDS-tiled fp32 GEMM. Block = 256 thr, 128 rows.
// Thread micro-tile 8 rows x 4 cols; X/W staged in LDS (16-k chunks);
// hidden kept in a 64-col LDS half buffer (48KB LDS total, 3 blocks/CU).
// ---------------------------------------------------------------------------

__device__ __forceinline__ unsigned fkey(float f) {
    unsigned u = __float_as_uint(f);
    return (u & 0x80000000u) ? ~u : (u | 0x80000000u);
}
__device__ __forceinline__ float funkey(unsigned k) {
    return (k & 0x80000000u) ? __uint_as_float(k & 0x7FFFFFFFu) : __uint_as_float(~k);
}

// out[M][64] = relu(X[M][K1] @ w1[K1][HID] + b1) @ w2[HID][64] + b2
// GATHER: X row e = concat(nf[src[e]], nf[tgt[e]], ef[e]); also atomicAdd into
// aggr[tgt[e]]. Non-gather: X = A0 rows.
template<int K1, int HID, bool GATHER>
__global__ __launch_bounds__(256)
void mlp2_gemm(const float* __restrict__ A0, const float* __restrict__ efp,
               const int* __restrict__ src, const int* __restrict__ tgt,
               const float* __restrict__ w1, const float* __restrict__ b1,
               const float* __restrict__ w2, const float* __restrict__ b2,
               float* __restrict__ outp, float* __restrict__ aggr, int M)
{
    __shared__ float Xs[16 * 128];   // X chunk, k-major [16][128]      (8KB)
    __shared__ float Ws1[16 * 64];   // w1 chunk [16][64-col half]      (4KB)
    __shared__ float Hs[64 * 128];   // relu(H) half, k2-major [64][128](32KB)
    __shared__ float Ws2[16 * 64];   // w2 chunk [16][64]               (4KB)

    const int tid = threadIdx.x;
    const int wave = tid >> 6, lane = tid & 63;
    const int e0 = blockIdx.x * 128;
    // wave tile: (wave&1) row-half of 64, (wave>>1) col-half of 32
    const int row0 = (wave & 1) * 64 + (lane & 7) * 8;
    const int col0 = (wave >> 1) * 32 + (lane >> 3) * 4;

    // staging assignment: rows rA and rA+64, float4 quad q
    const int rA = tid >> 2, q = tid & 3;
    int sA = 0, tA = 0, sB = 0, tB = 0;
    if (GATHER) {
        if (e0 + rA < M)      { sA = src[e0 + rA];      tA = tgt[e0 + rA]; }
        if (e0 + rA + 64 < M) { sB = src[e0 + rA + 64]; tB = tgt[e0 + rA + 64]; }
    }

    float acc2[32];
#pragma unroll
    for (int i = 0; i < 8; i++)
#pragma unroll
        for (int j = 0; j < 4; j++) acc2[i * 4 + j] = b2[col0 + j];

    const int HALVES = HID / 64;
#pragma unroll 1
    for (int ch = 0; ch < HALVES; ch++) {
        float acc1[32];
#pragma unroll
        for (int i = 0; i < 8; i++)
#pragma unroll
            for (int j = 0; j < 4; j++) acc1[i * 4 + j] = b1[ch * 64 + col0 + j];

        // ---- layer 1: H[:, ch*64 .. ch*64+64) ----
#pragma unroll 1
        for (int kc = 0; kc < K1; kc += 16) {
            // stage Xs[16][128] (transposed k-major)
            int r = rA;
#pragma unroll
            for (int h2 = 0; h2 < 2; h2++, r += 64) {
                const int e = e0 + r;
                float4 v = make_float4(0.f, 0.f, 0.f, 0.f);
                if (e < M) {
                    const float* p;
                    if (GATHER) {
                        const int region = kc >> 6;
                        const int koff = (kc & 63) + q * 4;
                        const int sidx = h2 ? sB : sA;
                        const int tidx = h2 ? tB : tA;
                        p = (region == 0) ? A0 + (size_t)sidx * 64 + koff
                          : (region == 1) ? A0 + (size_t)tidx * 64 + koff
                                          : efp + (size_t)e * 64 + koff;
                    } else {
                        p = A0 + (size_t)e * K1 + kc + q * 4;
                    }
                    v = *(const float4*)p;
                }
                Xs[(q * 4 + 0) * 128 + r] = v.x;
                Xs[(q * 4 + 1) * 128 + r] = v.y;
                Xs[(q * 4 + 2) * 128 + r] = v.z;
                Xs[(q * 4 + 3) * 128 + r] = v.w;
            }
            // stage Ws1[16][64]: w1[(kc+kk)][ch*64 + c]
            {
                const int kk = tid >> 4, c4 = (tid & 15) * 4;
                *(float4*)&Ws1[kk * 64 + c4] =
                    *(const float4*)&w1[(size_t)(kc + kk) * HID + ch * 64 + c4];
            }
            __syncthreads();
#pragma unroll
            for (int kk = 0; kk < 16; kk++) {
                float4 a0 = *(const float4*)&Xs[kk * 128 + row0];
                float4 a1 = *(const float4*)&Xs[kk * 128 + row0 + 4];
                float4 b  = *(const float4*)&Ws1[kk * 64 + col0];
                float ar[8] = {a0.x, a0.y, a0.z, a0.w, a1.x, a1.y, a1.z, a1.w};
                float br[4] = {b.x, b.y, b.z, b.w};
#pragma unroll
                for (int i = 0; i < 8; i++)
#pragma unroll
                    for (int j = 0; j < 4; j++)
                        acc1[i * 4 + j] = fmaf(ar[i], br[j], acc1[i * 4 + j]);
            }
            __syncthreads();
        }
        // write relu(H) transposed into Hs[k2][row]
#pragma unroll
        for (int j = 0; j < 4; j++) {
            float4 v0 = make_float4(fmaxf(acc1[0 * 4 + j], 0.f), fmaxf(acc1[1 * 4 + j], 0.f),
                                    fmaxf(acc1[2 * 4 + j], 0.f), fmaxf(acc1[3 * 4 + j], 0.f));
            float4 v1 = make_float4(fmaxf(acc1[4 * 4 + j], 0.f), fmaxf(acc1[5 * 4 + j], 0.f),
                                    fmaxf(acc1[6 * 4 + j], 0.f), fmaxf(acc1[7 * 4 + j], 0.f));
            *(float4*)&Hs[(col0 + j) * 128 + row0]     = v0;
            *(float4*)&Hs[(col0 + j) * 128 + row0 + 4] = v1;
        }
        __syncthreads();
        // ---- layer 2 partial: C += relu(H_half) @ w2[ch*64 .. ) ----
#pragma unroll 1
        for (int k2c = 0; k2c < 64; k2c += 16) {
            {
                const int kk = tid >> 4, c4 = (tid & 15) * 4;
                *(float4*)&Ws2[kk * 64 + c4] =
                    *(const float4*)&w2[(size_t)(ch * 64 + k2c + kk) * 64 + c4];
            }
            __syncthreads();
#pragma unroll
            for (int kk = 0; kk < 16; kk++) {
                float4 a0 = *(const float4*)&Hs[(k2c + kk) * 128 + row0];
                float4 a1 = *(const float4*)&Hs[(k2c + kk) * 128 + row0 + 4];
                float4 b  = *(const float4*)&Ws2[kk * 64 + col0];
                float ar[8] = {a0.x, a0.y, a0.z, a0.w, a1.x, a1.y, a1.z, a1.w};
                float br[4] = {b.x, b.y, b.z, b.w};
#pragma unroll
                for (int i = 0; i < 8; i++)
#pragma unroll
                    for (int j = 0; j < 4; j++)
                        acc2[i * 4 + j] = fmaf(ar[i], br[j], acc2[i * 4 + j]);
            }
            __syncthreads();
        }
    }
    // ---- epilogue ----
#pragma unroll
    for (int i = 0; i < 8; i++) {
        const int e = e0 + row0 + i;
        if (e < M)
            *(float4*)&outp[(size_t)e * 64 + col0] =
                make_float4(acc2[i * 4], acc2[i * 4 + 1], acc2[i * 4 + 2], acc2[i * 4 + 3]);
    }
    if (GATHER) {
#pragma unroll
        for (int i = 0; i < 8; i++) {
            const int e = e0 + row0 + i;
            if (e < M) {
                const int t = tgt[e];
                float* ag = aggr + (size_t)t * 64 + col0;
                atomicAdd(ag + 0, acc2[i * 4 + 0]);
                atomicAdd(ag + 1, acc2[i * 4 + 1]);
                atomicAdd(ag + 2, acc2[i * 4 + 2]);
                atomicAdd(ag + 3, acc2[i * 4 + 3]);
            }
        }
    }
}

// ---------------- small per-row helpers (unchanged from round 1) -----------
__device__ __forceinline__ void accum_part64(const float* __restrict__ xp,
                                             const float* __restrict__ w, const int wld,
                                             float* __restrict__ h)
{
#pragma unroll 1
    for (int kc = 0; kc < 64; kc += 8) {
        float4 a = *(const float4*)(xp + kc);
        float4 b = *(const float4*)(xp + kc + 4);
        float xs[8] = {a.x, a.y, a.z, a.w, b.x, b.y, b.z, b.w};
        const float* __restrict__ wr = w + (size_t)kc * wld;
#pragma unroll
        for (int kk = 0; kk < 8; kk++) {
#pragma unroll
            for (int c = 0; c < 64; c++)
                h[c] = fmaf(xs[kk], wr[(size_t)kk * wld + c], h[c]);
        }
    }
}

__device__ __forceinline__ void store_row64(float* __restrict__ dst, const float* __restrict__ acc)
{
#pragma unroll
    for (int i = 0; i < 16; i++)
        ((float4*)dst)[i] = make_float4(acc[4 * i], acc[4 * i + 1], acc[4 * i + 2], acc[4 * i + 3]);
}

// ---------------- node update: nf' = concat(nf, aggr) @ nu_w1 + b ----------
__global__ __launch_bounds__(64)
void node_update_kernel(const float* __restrict__ nf, const float* __restrict__ ag,
                        const float* __restrict__ w, const float* __restrict__ b,
                        float* __restrict__ out, int M)
{
    int r = blockIdx.x * 64 + threadIdx.x;
    if (r >= M) return;
    float acc[64];
#pragma unroll
    for (int c = 0; c < 64; c++) acc[c] = b[c];
    accum_part64(nf + (size_t)r * 64, w, 64, acc);
    accum_part64(ag + (size_t)r * 64, w + (size_t)64 * 64, 64, acc);
    store_row64(out + (size_t)r * 64, acc);
}

// ---------------- node heads ------------------------------------------------
__global__ __launch_bounds__(256)
void heads_kernel(const float* __restrict__ nf,
                  const float* __restrict__ nc_w1, const float* __restrict__ nc_b1,
                  const float* __restrict__ nc_w2, const float* __restrict__ nc_b2,
                  const float* __restrict__ cl_w1, const float* __restrict__ cl_b1,
                  const float* __restrict__ cl_w2, const float* __restrict__ cl_b2,
                  const float* __restrict__ ce_w,  const float* __restrict__ ce_b,
                  float* __restrict__ node_pred, float* __restrict__ class_pred,
                  int* __restrict__ ntype, float* __restrict__ emb, int M)
{
    int r = blockIdx.x * blockDim.x + threadIdx.x;
    if (r >= M) return;
    const float* xp = nf + (size_t)r * 64;
    {
        float h[64];
#pragma unroll
        for (int c = 0; c < 64; c++) h[c] = nc_b1[c];
        accum_part64(xp, nc_w1, 64, h);
        float np = nc_b2[0];
#pragma unroll
        for (int k = 0; k < 64; k++) np = fmaf(fmaxf(h[k], 0.f), nc_w2[k], np);
        node_pred[r] = np;
    }
    {
        float h[64];
#pragma unroll
        for (int c = 0; c < 64; c++) h[c] = cl_b1[c];
        accum_part64(xp, cl_w1, 64, h);
        float cp[17];
#pragma unroll
        for (int j = 0; j < 17; j++) cp[j] = cl_b2[j];
#pragma unroll
        for (int k = 0; k < 64; k++) {
            float hv = fmaxf(h[k], 0.f);
#pragma unroll
            for (int j = 0; j < 17; j++) cp[j] = fmaf(hv, cl_w2[k * 17 + j], cp[j]);
        }
#pragma unroll
        for (int j = 0; j < 17; j++) class_pred[(size_t)r * 17 + j] = cp[j];
        float best = cp[0]; int bi = 0;          // jnp.argmax: first max index
#pragma unroll
        for (int j = 1; j < 17; j++) { if (cp[j] > best) { best = cp[j]; bi = j; } }
        ntype[r] = bi;
    }
    {
        float acc[64];
#pragma unroll
        for (int c = 0; c < 64; c++) acc[c] = ce_b[c];
        accum_part64(xp, ce_w, 64, acc);
        store_row64(emb + (size_t)r * 64, acc);
    }
}

// ---------------- segment-softmax passes -----------------------------------
__global__ void init_seg_kernel(unsigned* __restrict__ segmaxu, float* __restrict__ segsum, int n)
{
    int i = blockIdx.x * blockDim.x + threadIdx.x;
    if (i < n) { segmaxu[i] = 0x007FFFFFu /* fkey(-inf) */; segsum[i] = 0.f; }
}

__global__ __launch_bounds__(64)
void edge1_kernel(const float* __restrict__ ef,
                  const float* __restrict__ ec_w1, const float* __restrict__ ec_b1,
                  const float* __restrict__ ec_w2, const float* __restrict__ ec_b2,
                  const float* __restrict__ emb, const int* __restrict__ src,
                  const int* __restrict__ tgt, const int* __restrict__ ntype,
                  float* __restrict__ score, float* __restrict__ sigb,
                  int* __restrict__ seg, unsigned* __restrict__ segmaxu, int E)
{
    int e = blockIdx.x * 64 + threadIdx.x;
    if (e >= E) return;
    float h[64];
#pragma unroll
    for (int c = 0; c < 64; c++) h[c] = ec_b1[c];
    accum_part64(ef + (size_t)e * 64, ec_w1, 64, h);
    float ep = ec_b2[0];
#pragma unroll
    for (int k = 0; k < 64; k++) ep = fmaf(fmaxf(h[k], 0.f), ec_w2[k], ep);
    sigb[e] = 1.f / (1.f + expf(-ep));

    int s = src[e], t = tgt[e];
    const float* ea = emb + (size_t)s * 64;
    const float* eb = emb + (size_t)t * 64;
    float sc = 0.f;
#pragma unroll 1
    for (int kc = 0; kc < 64; kc += 4) {
        float4 ua = *(const float4*)(ea + kc);
        float4 ub = *(const float4*)(eb + kc);
        sc = fmaf(ua.x, ub.x, sc); sc = fmaf(ua.y, ub.y, sc);
        sc = fmaf(ua.z, ub.z, sc); sc = fmaf(ua.w, ub.w, sc);
    }
    score[e] = sc;
    int sg = t * 17 + ntype[s];
    seg[e] = sg;
    atomicMax(segmaxu + sg, fkey(sc));
}

__global__ void edge2_kernel(const float* __restrict__ score, const int* __restrict__ seg,
                             const unsigned* __restrict__ segmaxu, float* __restrict__ segsum,
                             float* __restrict__ exb, int E)
{
    int e = blockIdx.x * blockDim.x + threadIdx.x;
    if (e >= E) return;
    int sg = seg[e];
    float ex = expf(score[e] - funkey(segmaxu[sg]));
    exb[e] = ex;
    atomicAdd(segsum + sg, ex);
}

__global__ void edge3_kernel(const float* __restrict__ exb, const int* __restrict__ seg,
                             const float* __restrict__ segsum, const float* __restrict__ sigb,
                             float* __restrict__ out_edge, int E)
{
    int e = blockIdx.x * blockDim.x + threadIdx.x;
    if (e >= E) return;
    out_edge[e] = exb[e] / segsum[seg[e]] * sigb[e];
}

// ---------------------------------------------------------------------------
extern "C" void kernel_launch(void* const* d_in, const int* in_sizes, int n_in,
                              void* d_out, int out_size, void* d_ws, size_t ws_size,
                              hipStream_t stream)
{
    const float* x          = (const float*)d_in[0];
    const float* edge_attr  = (const float*)d_in[1];
    const int*   edge_index = (const int*)d_in[2];
    const float* ne_w1 = (const float*)d_in[4],  *ne_b1 = (const float*)d_in[5];
    const float* ne_w2 = (const float*)d_in[6],  *ne_b2 = (const float*)d_in[7];
    const float* ee_w1 = (const float*)d_in[8],  *ee_b1 = (const float*)d_in[9];
    const float* ee_w2 = (const float*)d_in[10], *ee_b2 = (const float*)d_in[11];
    const float* me_w1 = (const float*)d_in[12], *me_b1 = (const float*)d_in[13];
    const float* me_w2 = (const float*)d_in[14], *me_b2 = (const float*)d_in[15];
    const float* nu_w1 = (const float*)d_in[16], *nu_b1 = (const float*)d_in[17];
    const float* ec_w1 = (const float*)d_in[18], *ec_b1 = (const float*)d_in[19];
    const float* ec_w2 = (const float*)d_in[20], *ec_b2 = (const float*)d_in[21];
    const float* nc_w1 = (const float*)d_in[22], *nc_b1 = (const float*)d_in[23];
    const float* nc_w2 = (const float*)d_in[24], *nc_b2 = (const float*)d_in[25];
    const float* cl_w1 = (const float*)d_in[26], *cl_b1 = (const float*)d_in[27];
    const float* cl_w2 = (const float*)d_in[28], *cl_b2 = (const float*)d_in[29];
    const float* ce_w  = (const float*)d_in[30], *ce_b  = (const float*)d_in[31];

    const int N = in_sizes[3];
    const int E = in_sizes[2] / 2;
    const int* src = edge_index;
    const int* tgt = edge_index + E;

    float* out      = (float*)d_out;
    float* out_edge = out;                              // [E]
    float* out_np   = out + E;                          // [N]
    float* out_cp   = out_np + N;                       // [N,17]
    float* out_nf   = out_cp + (size_t)17 * N;          // [N,64]
    float* out_ef   = out_nf + (size_t)64 * N;          // [E,64]

    float* p = (float*)d_ws;
    float* nfA    = p; p += (size_t)N * 64;
    float* nfB    = p; p += (size_t)N * 64;
    float* aggr   = p; p += (size_t)N * 64;
    float* emb    = p; p += (size_t)N * 64;
    float* efA    = p; p += (size_t)E * 64;
    float* score  = p; p += E;
    float* sigb   = p; p += E;
    float* exb    = p; p += E;
    float* segsum = p; p += (size_t)N * 17;
    unsigned* segmaxu = (unsigned*)p; p += (size_t)N * 17;
    int* seg   = (int*)p; p += E;
    int* ntype = (int*)p; p += N;

    const int gN128 = (N + 127) / 128, gE128 = (E + 127) / 128;
    const int gN = (N + 63) / 64, gE = (E + 63) / 64;

    // encoders (tiled GEMM)
    mlp2_gemm<64, 64, false><<<gN128, 256, 0, stream>>>(
        x, nullptr, nullptr, nullptr, ne_w1, ne_b1, ne_w2, ne_b2, nfA, nullptr, N);
    mlp2_gemm<64, 64, false><<<gE128, 256, 0, stream>>>(
        edge_attr, nullptr, nullptr, nullptr, ee_w1, ee_b1, ee_w2, ee_b2, efA, nullptr, E);

    // 3 MPN steps
    const float* nf_cur = nfA;
    const float* ef_cur = efA;
    for (int st = 0; st < 3; st++) {
        float* m_dst  = (st == 1) ? efA : out_ef;
        float* nf_dst = (st == 0) ? nfB : (st == 1) ? nfA : out_nf;
        hipMemsetAsync(aggr, 0, (size_t)N * 64 * sizeof(float), stream);
        mlp2_gemm<192, 128, true><<<gE128, 256, 0, stream>>>(
            nf_cur, ef_cur, src, tgt, me_w1, me_b1, me_w2, me_b2, m_dst, aggr, E);
        node_update_kernel<<<gN, 64, 0, stream>>>(nf_cur, aggr, nu_w1, nu_b1, nf_dst, N);
        nf_cur = nf_dst; ef_cur = m_dst;
    }

    // heads + type-constrained scatter-softmax
    heads_kernel<<<(N + 255) / 256, 256, 0, stream>>>(out_nf,
        nc_w1, nc_b1, nc_w2, nc_b2, cl_w1, cl_b1, cl_w2, cl_b2, ce_w, ce_b,
        out_np, out_cp, ntype, emb, N);
    init_seg_kernel<<<(N * 17 + 255) / 256, 256, 0, stream>>>(segmaxu, segsum, N * 17);
    edge1_kernel<<<gE, 64, 0, stream>>>(out_ef, ec_w1, ec_b1, ec_w2, ec_b2,
                                        emb, src, tgt, ntype, score, sigb, seg, segmaxu, E);
    edge2_kernel<<<(E + 255) / 256, 256, 0, stream>>>(score, seg, segmaxu, segsum, exb, E);
    edge3_kernel<<<(E + 255) / 256, 256, 0, stream>>>(exb, seg, segsum, sigb, out_edge, E);
}